// Round 2
// baseline (734.437 us; speedup 1.0000x reference)
//
#include <hip/hip_runtime.h>
#include <math.h>

#define B_ 16
#define L_ 4096
#define H_ 8
#define D_ 64
#define HD_ (H_*D_)     // 512
#define U_ 45
#define UP_ 48
#define NCHUNK 32
#define CHLEN 128       // L_/NCHUNK
#define VTP 20          // Vt pitch in dwords (16B-aligned rows, conflict-light)
#define PP  20          // P  pitch in dwords

typedef __attribute__((ext_vector_type(8))) short short8v;  // 8 bf16 (4 VGPRs)
typedef __attribute__((ext_vector_type(4))) float f32x4;

__device__ inline unsigned int pk2(float a, float b) {
    return (__float_as_uint(b) & 0xFFFF0000u) | (__float_as_uint(a) >> 16);
}
__device__ inline short8v u4cast(uint4 u) {
    union { uint4 u4; short8v s8; } c; c.u4 = u; return c.s8;
}

// ---------------- Phase A0: K_sample^2 precompute (enables scalar loads in kM) ----------------
__global__ __launch_bounds__(256) void kK2(const float* __restrict__ K, const int* __restrict__ idx,
                                           int S, float* __restrict__ k2) {
    int bh = blockIdx.x;
    int b = bh >> 3, h = bh & 7;
    for (int i = threadIdx.x; i < S * D_; i += 256) {
        int s = i >> 6, d = i & 63;
        float kv = K[(((size_t)b * L_ + idx[s]) * H_ + h) * D_ + d];
        k2[(size_t)bh * (45 * 64) + i] = kv * kv;
    }
}

// ---------------- Phase A: sparsity measure M (fp32; k2 via wave-uniform scalar loads) ----------------
// Accumulation order identical to previous passing kernel -> bitwise-identical M -> top-k unchanged.
__global__ __launch_bounds__(256) void kM(const float* __restrict__ Q, const float* __restrict__ k2g,
                                          int S, float* __restrict__ M) {
    int blk = blockIdx.x;
    int chunk = blk & 15;
    int bh = blk >> 4;
    int b = bh >> 3, h = bh & 7;
    int q = chunk * 256 + threadIdx.x;
    const float4* qp = (const float4*)(Q + (((size_t)b * L_ + q) * H_ + h) * D_);
    float4 qr[16];
#pragma unroll
    for (int c = 0; c < 16; c++) qr[c] = qp[c];
    const float4* kp0 = (const float4*)(k2g + (size_t)bh * (45 * 64));
    float mx = -INFINITY, sm = 0.f;
    for (int s = 0; s < S; s++) {
        const float4* kp = kp0 + s * 16;   // uniform across wave -> s_load
        float d0 = 0, d1 = 0, d2 = 0, d3 = 0;
#pragma unroll
        for (int c = 0; c < 16; c++) {
            float4 kv = kp[c];
            d0 += qr[c].x * kv.x; d1 += qr[c].y * kv.y;
            d2 += qr[c].z * kv.z; d3 += qr[c].w * kv.w;
        }
        float dot = (d0 + d1) + (d2 + d3);
        mx = fmaxf(mx, dot); sm += dot;
    }
    M[(size_t)bh * L_ + q] = mx - sm * (1.0f / (float)L_);
}

// ---------------- Phase B: top-45 per (b,h), register-resident iterative argmax ----------------
__global__ __launch_bounds__(256) void kTop(const float* __restrict__ M, int* __restrict__ mtop) {
    int bh = blockIdx.x, t = threadIdx.x;
    int lane = t & 63, wid = t >> 6;
    float mv[16];
#pragma unroll
    for (int w = 0; w < 16; w++) mv[w] = M[(size_t)bh * L_ + w * 256 + t];
    __shared__ float swv[4];
    __shared__ int swi[4];
    for (int it = 0; it < U_; it++) {
        float bv = -INFINITY; int bi = 1 << 30;
#pragma unroll
        for (int w = 0; w < 16; w++) {
            if (mv[w] > bv) { bv = mv[w]; bi = w * 256 + t; }
        }
#pragma unroll
        for (int off = 1; off < 64; off <<= 1) {
            float ov = __shfl_xor(bv, off); int oi = __shfl_xor(bi, off);
            if (ov > bv || (ov == bv && oi < bi)) { bv = ov; bi = oi; }
        }
        if (lane == 0) { swv[wid] = bv; swi[wid] = bi; }
        __syncthreads();
        float fv = swv[0]; int fi = swi[0];
        for (int w2 = 1; w2 < 4; w2++) {
            if (swv[w2] > fv || (swv[w2] == fv && swi[w2] < fi)) { fv = swv[w2]; fi = swi[w2]; }
        }
        if (t == 0) mtop[bh * U_ + it] = fi;
        int wr = fi >> 8;
        bool own = ((fi & 255) == t);
#pragma unroll
        for (int w = 0; w < 16; w++) mv[w] = (own && w == wr) ? -INFINITY : mv[w];
        __syncthreads();
    }
}

// ---------------- Phase C: chunked cumsum of V -> out ----------------
__global__ __launch_bounds__(64) void kSum(const float* __restrict__ V, float* __restrict__ cs) {
    int blk = blockIdx.x;
    int c = blk & 31, bh = blk >> 5;
    int b = bh >> 3, h = bh & 7;
    size_t base = (((size_t)b * L_ + c * CHLEN) * H_ + h) * D_ + threadIdx.x;
    float acc = 0.f;
#pragma unroll 8
    for (int i = 0; i < CHLEN; i++) acc += V[base + (size_t)i * HD_];
    cs[((size_t)bh * NCHUNK + c) * D_ + threadIdx.x] = acc;
}

__global__ __launch_bounds__(64) void kScan(float* __restrict__ cs) {
    int bh = blockIdx.x;
    int d = threadIdx.x;
    float run = 0.f;
    for (int c = 0; c < NCHUNK; c++) {
        size_t i = ((size_t)bh * NCHUNK + c) * D_ + d;
        float t = cs[i]; cs[i] = run; run += t;
    }
}

__global__ __launch_bounds__(64) void kCum(const float* __restrict__ V, const float* __restrict__ cs,
                                           float* __restrict__ out) {
    int blk = blockIdx.x;
    int c = blk & 31, bh = blk >> 5;
    int b = bh >> 3, h = bh & 7;
    size_t base = (((size_t)b * L_ + c * CHLEN) * H_ + h) * D_ + threadIdx.x;
    float acc = cs[((size_t)bh * NCHUNK + c) * D_ + threadIdx.x];
#pragma unroll 4
    for (int i = 0; i < CHLEN; i++) {
        acc += V[base + (size_t)i * HD_];
        out[base + (size_t)i * HD_] = acc;
    }
}

// ---------------- Phase D: per-wave-independent split-K flash attention (MFMA bf16) ----------------
// Block = 128 thr (2 waves). Each wave owns k-range [(ks*2+wave)*wkspan, +wkspan), has its own
// Vt/P LDS buffers, zero in-loop barriers.
// GEMM1 (swapped): S^T[key][q] = mfma(A=K rows, B=Q rows) -> both operands are natural
//   row-major bf16x8 global loads; C layout: q = lane&15, key = jt + n*16 + (lane>>4)*4 + reg.
// Softmax reduce over keys = in-register fold + shfl_xor(16,32).
// GEMM2: O^T[d][q] = mfma(A=Vt rows (V transposed in LDS), B=P rows (P in LDS [q][k] bf16)).
__global__ __launch_bounds__(128) void kFlash(const float* __restrict__ Q, const float* __restrict__ K,
                                              const float* __restrict__ V, const int* __restrict__ mtop,
                                              float* __restrict__ Opart, float* __restrict__ mpart,
                                              float* __restrict__ lpart, int nsb, int wkspan) {
    int blk = blockIdx.x;
    int ks = blk % nsb;
    int bh = blk / nsb;
    int b = bh >> 3, h = bh & 7;
    int tid = threadIdx.x, wave = tid >> 6, lane = tid & 63;
    int q16 = lane & 15, g = lane >> 4;

    __shared__ __align__(16) unsigned int VtS[2][64 * VTP];   // per-wave V^T tile (also O bounce)
    __shared__ __align__(16) unsigned int PS[2][UP_ * PP];    // per-wave P tile [q][k] bf16
    __shared__ int mt[UP_];
    __shared__ int kmaxs;

    unsigned int* Vt = VtS[wave];
    unsigned int* P = PS[wave];

    if (tid < UP_) mt[tid] = (tid < U_) ? mtop[bh * U_ + tid] : -1;
    __syncthreads();
    if (tid == 0) {
        int km = 0;
        for (int u = 0; u < U_; u++) km = max(km, mt[u] + 1);
        kmaxs = km;
    }

    // Q fragments in registers (B-frag: q = lane&15 per tile, d = (lane>>4)*8 + s*32 + j), pre-scaled.
    int mtr[3];
    short8v qf[3][2];
#pragma unroll
    for (int t = 0; t < 3; t++) {
        int qi = t * 16 + q16;
        mtr[t] = mt[qi];
        int r = mtr[t] < 0 ? 0 : mtr[t];
        const float* qrow = Q + (((size_t)b * L_ + r) * H_ + h) * D_;
#pragma unroll
        for (int s = 0; s < 2; s++) {
            int d0 = s * 32 + g * 8;
            float4 f0 = *(const float4*)(qrow + d0);
            float4 f1 = *(const float4*)(qrow + d0 + 4);
            uint4 u;
            u.x = pk2(f0.x * 0.125f, f0.y * 0.125f);
            u.y = pk2(f0.z * 0.125f, f0.w * 0.125f);
            u.z = pk2(f1.x * 0.125f, f1.y * 0.125f);
            u.w = pk2(f1.z * 0.125f, f1.w * 0.125f);
            qf[t][s] = u4cast(u);
        }
    }
    __syncthreads();

    f32x4 Oa[4][3];   // [dtile][qtile]; C: q = lane&15, d = dt*16 + (lane>>4)*4 + reg
#pragma unroll
    for (int dt = 0; dt < 4; dt++)
#pragma unroll
        for (int t = 0; t < 3; t++) Oa[dt][t] = (f32x4){0.f, 0.f, 0.f, 0.f};
    float mrow[3] = {-INFINITY, -INFINITY, -INFINITY};
    float lrow[3] = {0.f, 0.f, 0.f};

    int ko = (ks * 2 + wave) * wkspan;
    int kend = min(kmaxs, ko + wkspan);

    for (int jt = ko; jt < kend; jt += 32) {
        // ---- issue V loads early (consumed after GEMM1/softmax) ----
        const float* vrow0 = V + (((size_t)b * L_ + jt + 2 * q16) * H_ + h) * D_;
        const float* vrow1 = vrow0 + HD_;
        float4 va[4], vb[4];
#pragma unroll
        for (int i = 0; i < 4; i++) {
            int d0 = i * 16 + g * 4;
            va[i] = *(const float4*)(vrow0 + d0);
            vb[i] = *(const float4*)(vrow1 + d0);
        }
        // ---- K fragments from global + GEMM1 ----
        f32x4 Sa[3][2];
#pragma unroll
        for (int t = 0; t < 3; t++)
#pragma unroll
            for (int n = 0; n < 2; n++) Sa[t][n] = (f32x4){0.f, 0.f, 0.f, 0.f};
#pragma unroll
        for (int s = 0; s < 2; s++) {
            short8v kf[2];
#pragma unroll
            for (int n = 0; n < 2; n++) {
                const float* krow = K + (((size_t)b * L_ + jt + n * 16 + q16) * H_ + h) * D_ + s * 32 + g * 8;
                float4 f0 = *(const float4*)krow;
                float4 f1 = *(const float4*)(krow + 4);
                uint4 u;
                u.x = pk2(f0.x, f0.y); u.y = pk2(f0.z, f0.w);
                u.z = pk2(f1.x, f1.y); u.w = pk2(f1.z, f1.w);
                kf[n] = u4cast(u);
            }
#pragma unroll
            for (int t = 0; t < 3; t++)
#pragma unroll
                for (int n = 0; n < 2; n++)
                    Sa[t][n] = __builtin_amdgcn_mfma_f32_16x16x32_bf16(kf[n], qf[t][s], Sa[t][n], 0, 0, 0);
        }
        // ---- online softmax per q-tile (keys in-lane + shfl_xor over groups) ----
#pragma unroll
        for (int t = 0; t < 3; t++) {
            int limit = mtr[t];
            int kb = jt + g * 4;
            float p[2][4];
            float pmax = -INFINITY;
#pragma unroll
            for (int n = 0; n < 2; n++)
#pragma unroll
                for (int r = 0; r < 4; r++) {
                    float sv = (kb + n * 16 + r <= limit) ? Sa[t][n][r] : -INFINITY;
                    p[n][r] = sv;
                    pmax = fmaxf(pmax, sv);
                }
            pmax = fmaxf(pmax, __shfl_xor(pmax, 16));
            pmax = fmaxf(pmax, __shfl_xor(pmax, 32));
            float nm = fmaxf(mrow[t], pmax);
            float alpha = (nm == -INFINITY) ? 1.f : __expf(mrow[t] - nm);
            mrow[t] = nm;
            float rs = 0.f;
#pragma unroll
            for (int n = 0; n < 2; n++)
#pragma unroll
                for (int r = 0; r < 4; r++) {
                    float pv = (p[n][r] == -INFINITY) ? 0.f : __expf(p[n][r] - nm);
                    p[n][r] = pv; rs += pv;
                }
            rs += __shfl_xor(rs, 16);
            rs += __shfl_xor(rs, 32);
            lrow[t] = lrow[t] * alpha + rs;
            int qi = t * 16 + q16;
#pragma unroll
            for (int n = 0; n < 2; n++) {
                *(uint2*)&P[qi * PP + n * 8 + 2 * g] =
                    make_uint2(pk2(p[n][0], p[n][1]), pk2(p[n][2], p[n][3]));
            }
#pragma unroll
            for (int dt = 0; dt < 4; dt++)
#pragma unroll
                for (int r = 0; r < 4; r++) Oa[dt][t][r] *= alpha;
        }
        // ---- stage V^T (keys packed in pairs along rows of d) ----
#pragma unroll
        for (int i = 0; i < 4; i++) {
            int d0 = i * 16 + g * 4;
#pragma unroll
            for (int c = 0; c < 4; c++) {
                float fa = (&va[i].x)[c], fb = (&vb[i].x)[c];
                Vt[(d0 + c) * VTP + q16] = pk2(fa, fb);
            }
        }
        // ---- GEMM2: O^T += Vt . P ----
        short8v pb[3];
#pragma unroll
        for (int t = 0; t < 3; t++)
            pb[t] = u4cast(*(uint4*)&P[(t * 16 + q16) * PP + g * 4]);
#pragma unroll
        for (int dt = 0; dt < 4; dt++) {
            short8v vf = u4cast(*(uint4*)&Vt[(dt * 16 + q16) * VTP + g * 4]);
#pragma unroll
            for (int t = 0; t < 3; t++)
                Oa[dt][t] = __builtin_amdgcn_mfma_f32_16x16x32_bf16(vf, pb[t], Oa[dt][t], 0, 0, 0);
        }
    }

    // ---- epilogue: bounce O through LDS (Vt buffer, free now) for coalesced stores ----
    int nse = nsb * 2;
    int e = ks * 2 + wave;
    float* ob = Opart + ((size_t)(bh * nse + e)) * UP_ * D_;
    int q2 = lane >> 2, c2 = lane & 3;
#pragma unroll
    for (int t = 0; t < 3; t++) {
#pragma unroll
        for (int dt = 0; dt < 4; dt++) {
            f32x4 o = Oa[dt][t];
            *(uint4*)&Vt[q16 * 68 + dt * 16 + g * 4] =
                make_uint4(__float_as_uint(o[0]), __float_as_uint(o[1]),
                           __float_as_uint(o[2]), __float_as_uint(o[3]));
        }
#pragma unroll
        for (int j = 0; j < 4; j++) {
            uint4 u = *(uint4*)&Vt[q2 * 68 + j * 16 + c2 * 4];
            *(float4*)(ob + (size_t)(t * 16 + q2) * D_ + j * 16 + c2 * 4) =
                make_float4(__uint_as_float(u.x), __uint_as_float(u.y),
                            __uint_as_float(u.z), __uint_as_float(u.w));
        }
        if (g == 0) {
            int qi = t * 16 + q16;
            mpart[(size_t)(bh * nse + e) * UP_ + qi] = mrow[t];
            lpart[(size_t)(bh * nse + e) * UP_ + qi] = lrow[t];
        }
    }
}

// ---------------- Phase E: merge split partials, scatter into out ----------------
__global__ __launch_bounds__(256) void kMerge(const float* __restrict__ Opart, const float* __restrict__ mpart,
                                              const float* __restrict__ lpart, const int* __restrict__ mtop,
                                              float* __restrict__ out, int nse) {
    int bh = blockIdx.x; int b = bh >> 3, h = bh & 7;
    for (int idx = threadIdx.x; idx < U_ * D_; idx += 256) {
        int q = idx >> 6, d = idx & 63;
        float mmax = -INFINITY;
        for (int i = 0; i < nse; i++) mmax = fmaxf(mmax, mpart[(size_t)(bh * nse + i) * UP_ + q]);
        float Ls = 0.f, val = 0.f;
        for (int i = 0; i < nse; i++) {
            float w = __expf(mpart[(size_t)(bh * nse + i) * UP_ + q] - mmax);
            Ls += lpart[(size_t)(bh * nse + i) * UP_ + q] * w;
            val += Opart[((size_t)(bh * nse + i) * UP_ + q) * D_ + d] * w;
        }
        int m = mtop[bh * U_ + q];
        out[(((size_t)b * L_ + m) * H_ + h) * D_ + d] = val / Ls;
    }
}

extern "C" void kernel_launch(void* const* d_in, const int* in_sizes, int n_in,
                              void* d_out, int out_size, void* d_ws, size_t ws_size,
                              hipStream_t stream) {
    const float* Q = (const float*)d_in[0];
    const float* K = (const float*)d_in[1];
    const float* V = (const float*)d_in[2];
    const int* idx = (const int*)d_in[3];
    int S = in_sizes[3]; if (S > 45) S = 45;
    float* out = (float*)d_out;
    float* ws = (float*)d_ws;

    // Adaptive split count: 2*nsb effective splits; Opart = 128*2*nsb*48*64 floats.
    size_t wsf = ws_size / 4;
    int nsb = 16;
    while (nsb > 1) {
        size_t opart = (size_t)128 * (2 * nsb) * UP_ * D_;
        size_t need = 5760 + opart + 2 * (size_t)128 * (2 * nsb) * UP_;
        size_t needAB = 5760 + 524288 + 262144 + 368640;   // M + cs + k2 phase
        if (need <= wsf && needAB <= wsf) break;
        nsb >>= 1;
    }
    int nse = 2 * nsb;

    // layout: [mtop][ region shared by {M,cs,k2} (phases A-C) and {Opart,mpart,lpart} (phases D-E) ]
    int* mtop = (int*)ws;
    float* rest = ws + 5760;
    float* M = rest;
    float* cs = rest + 524288;
    float* k2 = rest + 524288 + 262144;
    float* Opart = rest;
    float* mpart = Opart + (size_t)128 * nse * UP_ * D_;
    float* lpart = mpart + (size_t)128 * nse * UP_;

    kK2  <<<B_ * H_,              256, 0, stream>>>(K, idx, S, k2);
    kM   <<<B_ * H_ * (L_ / 256), 256, 0, stream>>>(Q, k2, S, M);
    kTop <<<B_ * H_,              256, 0, stream>>>(M, mtop);
    kSum <<<B_ * H_ * NCHUNK,      64, 0, stream>>>(V, cs);
    kScan<<<B_ * H_,               64, 0, stream>>>(cs);
    kCum <<<B_ * H_ * NCHUNK,      64, 0, stream>>>(V, cs, out);
    kFlash<<<B_ * H_ * nsb,       128, 0, stream>>>(Q, K, V, mtop, Opart, mpart, lpart, nsb, L_ / nse);
    kMerge<<<B_ * H_,             256, 0, stream>>>(Opart, mpart, lpart, mtop, out, nse);
}

// Round 3
// 611.084 us; speedup vs baseline: 1.2019x; 1.2019x over previous
//
#include <hip/hip_runtime.h>
#include <math.h>

#define B_ 16
#define L_ 4096
#define H_ 8
#define D_ 64
#define HD_ (H_*D_)     // 512
#define U_ 45
#define UP_ 48
#define NCHUNK 32
#define CHLEN 128       // L_/NCHUNK
#define VTP 20          // Vt pitch in dwords (16B-aligned rows, conflict-light)
#define PP  20          // P  pitch in dwords

typedef __attribute__((ext_vector_type(8))) short short8v;  // 8 bf16 (4 VGPRs)
typedef __attribute__((ext_vector_type(4))) float f32x4;

__device__ inline unsigned int pk2(float a, float b) {
    return (__float_as_uint(b) & 0xFFFF0000u) | (__float_as_uint(a) >> 16);
}
__device__ inline short8v u4cast(uint4 u) {
    union { uint4 u4; short8v s8; } c; c.u4 = u; return c.s8;
}

// ---------------- Phase A0: K_sample^2 precompute (enables scalar loads in kM) ----------------
__global__ __launch_bounds__(256) void kK2(const float* __restrict__ K, const int* __restrict__ idx,
                                           int S, float* __restrict__ k2) {
    int bh = blockIdx.x;
    int b = bh >> 3, h = bh & 7;
    for (int i = threadIdx.x; i < S * D_; i += 256) {
        int s = i >> 6, d = i & 63;
        float kv = K[(((size_t)b * L_ + idx[s]) * H_ + h) * D_ + d];
        k2[(size_t)bh * (45 * 64) + i] = kv * kv;
    }
}

// ---------------- Phase A: sparsity measure M (fp32; k2 via wave-uniform scalar loads) ----------------
// Accumulation order identical to previous passing kernel -> bitwise-identical M -> top-k unchanged.
__global__ __launch_bounds__(256) void kM(const float* __restrict__ Q, const float* __restrict__ k2g,
                                          int S, float* __restrict__ M) {
    int blk = blockIdx.x;
    int chunk = blk & 15;
    int bh = blk >> 4;
    int b = bh >> 3, h = bh & 7;
    int q = chunk * 256 + threadIdx.x;
    const float4* qp = (const float4*)(Q + (((size_t)b * L_ + q) * H_ + h) * D_);
    float4 qr[16];
#pragma unroll
    for (int c = 0; c < 16; c++) qr[c] = qp[c];
    const float4* kp0 = (const float4*)(k2g + (size_t)bh * (45 * 64));
    float mx = -INFINITY, sm = 0.f;
    for (int s = 0; s < S; s++) {
        const float4* kp = kp0 + s * 16;   // uniform across wave -> s_load
        float d0 = 0, d1 = 0, d2 = 0, d3 = 0;
#pragma unroll
        for (int c = 0; c < 16; c++) {
            float4 kv = kp[c];
            d0 += qr[c].x * kv.x; d1 += qr[c].y * kv.y;
            d2 += qr[c].z * kv.z; d3 += qr[c].w * kv.w;
        }
        float dot = (d0 + d1) + (d2 + d3);
        mx = fmaxf(mx, dot); sm += dot;
    }
    M[(size_t)bh * L_ + q] = mx - sm * (1.0f / (float)L_);
}

// ---------------- Phase B: top-45 per (b,h), register-resident iterative argmax ----------------
__global__ __launch_bounds__(256) void kTop(const float* __restrict__ M, int* __restrict__ mtop) {
    int bh = blockIdx.x, t = threadIdx.x;
    int lane = t & 63, wid = t >> 6;
    float mv[16];
#pragma unroll
    for (int w = 0; w < 16; w++) mv[w] = M[(size_t)bh * L_ + w * 256 + t];
    __shared__ float swv[4];
    __shared__ int swi[4];
    for (int it = 0; it < U_; it++) {
        float bv = -INFINITY; int bi = 1 << 30;
#pragma unroll
        for (int w = 0; w < 16; w++) {
            if (mv[w] > bv) { bv = mv[w]; bi = w * 256 + t; }
        }
#pragma unroll
        for (int off = 1; off < 64; off <<= 1) {
            float ov = __shfl_xor(bv, off); int oi = __shfl_xor(bi, off);
            if (ov > bv || (ov == bv && oi < bi)) { bv = ov; bi = oi; }
        }
        if (lane == 0) { swv[wid] = bv; swi[wid] = bi; }
        __syncthreads();
        float fv = swv[0]; int fi = swi[0];
        for (int w2 = 1; w2 < 4; w2++) {
            if (swv[w2] > fv || (swv[w2] == fv && swi[w2] < fi)) { fv = swv[w2]; fi = swi[w2]; }
        }
        if (t == 0) mtop[bh * U_ + it] = fi;
        int wr = fi >> 8;
        bool own = ((fi & 255) == t);
#pragma unroll
        for (int w = 0; w < 16; w++) mv[w] = (own && w == wr) ? -INFINITY : mv[w];
        __syncthreads();
    }
}

// ---------------- Phase C: chunked cumsum of V -> out ----------------
__global__ __launch_bounds__(64) void kSum(const float* __restrict__ V, float* __restrict__ cs) {
    int blk = blockIdx.x;
    int c = blk & 31, bh = blk >> 5;
    int b = bh >> 3, h = bh & 7;
    size_t base = (((size_t)b * L_ + c * CHLEN) * H_ + h) * D_ + threadIdx.x;
    float acc = 0.f;
#pragma unroll 8
    for (int i = 0; i < CHLEN; i++) acc += V[base + (size_t)i * HD_];
    cs[((size_t)bh * NCHUNK + c) * D_ + threadIdx.x] = acc;
}

__global__ __launch_bounds__(64) void kScan(float* __restrict__ cs) {
    int bh = blockIdx.x;
    int d = threadIdx.x;
    float run = 0.f;
    for (int c = 0; c < NCHUNK; c++) {
        size_t i = ((size_t)bh * NCHUNK + c) * D_ + d;
        float t = cs[i]; cs[i] = run; run += t;
    }
}

__global__ __launch_bounds__(64) void kCum(const float* __restrict__ V, const float* __restrict__ cs,
                                           float* __restrict__ out) {
    int blk = blockIdx.x;
    int c = blk & 31, bh = blk >> 5;
    int b = bh >> 3, h = bh & 7;
    size_t base = (((size_t)b * L_ + c * CHLEN) * H_ + h) * D_ + threadIdx.x;
    float acc = cs[((size_t)bh * NCHUNK + c) * D_ + threadIdx.x];
#pragma unroll 4
    for (int i = 0; i < CHLEN; i++) {
        acc += V[base + (size_t)i * HD_];
        out[base + (size_t)i * HD_] = acc;
    }
}

// ---------------- Phase D: per-wave-independent split-K flash attention (MFMA bf16) ----------------
__global__ __launch_bounds__(128) void kFlash(const float* __restrict__ Q, const float* __restrict__ K,
                                              const float* __restrict__ V, const int* __restrict__ mtop,
                                              float* __restrict__ Opart, float* __restrict__ mpart,
                                              float* __restrict__ lpart, int nsb, int wkspan) {
    int blk = blockIdx.x;
    int ks = blk % nsb;
    int bh = blk / nsb;
    int b = bh >> 3, h = bh & 7;
    int tid = threadIdx.x, wave = tid >> 6, lane = tid & 63;
    int q16 = lane & 15, g = lane >> 4;

    __shared__ __align__(16) unsigned int VtS[2][64 * VTP];   // per-wave V^T tile (also O bounce)
    __shared__ __align__(16) unsigned int PS[2][UP_ * PP];    // per-wave P tile [q][k] bf16
    __shared__ int mt[UP_];
    __shared__ int kmaxs;

    unsigned int* Vt = VtS[wave];
    unsigned int* P = PS[wave];

    if (tid < UP_) mt[tid] = (tid < U_) ? mtop[bh * U_ + tid] : -1;
    __syncthreads();
    if (tid == 0) {
        int km = 0;
        for (int u = 0; u < U_; u++) km = max(km, mt[u] + 1);
        kmaxs = km;
    }

    // Q fragments in registers (B-frag: q = lane&15 per tile, d = (lane>>4)*8 + s*32 + j), pre-scaled.
    int mtr[3];
    short8v qf[3][2];
#pragma unroll
    for (int t = 0; t < 3; t++) {
        int qi = t * 16 + q16;
        mtr[t] = mt[qi];
        int r = mtr[t] < 0 ? 0 : mtr[t];
        const float* qrow = Q + (((size_t)b * L_ + r) * H_ + h) * D_;
#pragma unroll
        for (int s = 0; s < 2; s++) {
            int d0 = s * 32 + g * 8;
            float4 f0 = *(const float4*)(qrow + d0);
            float4 f1 = *(const float4*)(qrow + d0 + 4);
            uint4 u;
            u.x = pk2(f0.x * 0.125f, f0.y * 0.125f);
            u.y = pk2(f0.z * 0.125f, f0.w * 0.125f);
            u.z = pk2(f1.x * 0.125f, f1.y * 0.125f);
            u.w = pk2(f1.z * 0.125f, f1.w * 0.125f);
            qf[t][s] = u4cast(u);
        }
    }
    __syncthreads();

    f32x4 Oa[4][3];   // [dtile][qtile]; C: q = lane&15, d = dt*16 + (lane>>4)*4 + reg
#pragma unroll
    for (int dt = 0; dt < 4; dt++)
#pragma unroll
        for (int t = 0; t < 3; t++) Oa[dt][t] = (f32x4){0.f, 0.f, 0.f, 0.f};
    float mrow[3] = {-INFINITY, -INFINITY, -INFINITY};
    float lrow[3] = {0.f, 0.f, 0.f};

    int ko = (ks * 2 + wave) * wkspan;
    int kend = min(kmaxs, ko + wkspan);

    for (int jt = ko; jt < kend; jt += 32) {
        // ---- issue V loads early (consumed after GEMM1/softmax) ----
        const float* vrow0 = V + (((size_t)b * L_ + jt + 2 * q16) * H_ + h) * D_;
        const float* vrow1 = vrow0 + HD_;
        float4 va[4], vb[4];
#pragma unroll
        for (int i = 0; i < 4; i++) {
            int d0 = i * 16 + g * 4;
            va[i] = *(const float4*)(vrow0 + d0);
            vb[i] = *(const float4*)(vrow1 + d0);
        }
        // ---- K fragments from global + GEMM1 ----
        f32x4 Sa[3][2];
#pragma unroll
        for (int t = 0; t < 3; t++)
#pragma unroll
            for (int n = 0; n < 2; n++) Sa[t][n] = (f32x4){0.f, 0.f, 0.f, 0.f};
#pragma unroll
        for (int s = 0; s < 2; s++) {
            short8v kf[2];
#pragma unroll
            for (int n = 0; n < 2; n++) {
                const float* krow = K + (((size_t)b * L_ + jt + n * 16 + q16) * H_ + h) * D_ + s * 32 + g * 8;
                float4 f0 = *(const float4*)krow;
                float4 f1 = *(const float4*)(krow + 4);
                uint4 u;
                u.x = pk2(f0.x, f0.y); u.y = pk2(f0.z, f0.w);
                u.z = pk2(f1.x, f1.y); u.w = pk2(f1.z, f1.w);
                kf[n] = u4cast(u);
            }
#pragma unroll
            for (int t = 0; t < 3; t++)
#pragma unroll
                for (int n = 0; n < 2; n++)
                    Sa[t][n] = __builtin_amdgcn_mfma_f32_16x16x32_bf16(kf[n], qf[t][s], Sa[t][n], 0, 0, 0);
        }
        // ---- online softmax per q-tile (keys in-lane + shfl_xor over groups) ----
#pragma unroll
        for (int t = 0; t < 3; t++) {
            int limit = mtr[t];
            int kb = jt + g * 4;
            float p[2][4];
            float pmax = -INFINITY;
#pragma unroll
            for (int n = 0; n < 2; n++)
#pragma unroll
                for (int r = 0; r < 4; r++) {
                    float sv = (kb + n * 16 + r <= limit) ? Sa[t][n][r] : -INFINITY;
                    p[n][r] = sv;
                    pmax = fmaxf(pmax, sv);
                }
            pmax = fmaxf(pmax, __shfl_xor(pmax, 16));
            pmax = fmaxf(pmax, __shfl_xor(pmax, 32));
            float nm = fmaxf(mrow[t], pmax);
            float alpha = (nm == -INFINITY) ? 1.f : __expf(mrow[t] - nm);
            mrow[t] = nm;
            float rs = 0.f;
#pragma unroll
            for (int n = 0; n < 2; n++)
#pragma unroll
                for (int r = 0; r < 4; r++) {
                    float pv = (p[n][r] == -INFINITY) ? 0.f : __expf(p[n][r] - nm);
                    p[n][r] = pv; rs += pv;
                }
            rs += __shfl_xor(rs, 16);
            rs += __shfl_xor(rs, 32);
            lrow[t] = lrow[t] * alpha + rs;
            int qi = t * 16 + q16;
#pragma unroll
            for (int n = 0; n < 2; n++) {
                *(uint2*)&P[qi * PP + n * 8 + 2 * g] =
                    make_uint2(pk2(p[n][0], p[n][1]), pk2(p[n][2], p[n][3]));
            }
#pragma unroll
            for (int dt = 0; dt < 4; dt++)
#pragma unroll
                for (int r = 0; r < 4; r++) Oa[dt][t][r] *= alpha;
        }
        // ---- stage V^T (keys packed in pairs along rows of d) ----
#pragma unroll
        for (int i = 0; i < 4; i++) {
            int d0 = i * 16 + g * 4;
#pragma unroll
            for (int c = 0; c < 4; c++) {
                float fa = (&va[i].x)[c], fb = (&vb[i].x)[c];
                Vt[(d0 + c) * VTP + q16] = pk2(fa, fb);
            }
        }
        // ---- GEMM2: O^T += Vt . P ----
        short8v pb[3];
#pragma unroll
        for (int t = 0; t < 3; t++)
            pb[t] = u4cast(*(uint4*)&P[(t * 16 + q16) * PP + g * 4]);
#pragma unroll
        for (int dt = 0; dt < 4; dt++) {
            short8v vf = u4cast(*(uint4*)&Vt[(dt * 16 + q16) * VTP + g * 4]);
#pragma unroll
            for (int t = 0; t < 3; t++)
                Oa[dt][t] = __builtin_amdgcn_mfma_f32_16x16x32_bf16(vf, pb[t], Oa[dt][t], 0, 0, 0);
        }
    }

    // ---- epilogue: write m/l always; O only if this wave covered any keys ----
    int nse = nsb * 2;
    int e = ks * 2 + wave;
    if (g == 0) {
#pragma unroll
        for (int t = 0; t < 3; t++) {
            int qi = t * 16 + q16;
            mpart[(size_t)(bh * nse + e) * UP_ + qi] = mrow[t];
            lpart[(size_t)(bh * nse + e) * UP_ + qi] = lrow[t];
        }
    }
    if (kend > ko) {
        float* ob = Opart + ((size_t)(bh * nse + e)) * UP_ * D_;
        int q2 = lane >> 2, c2 = lane & 3;
#pragma unroll
        for (int t = 0; t < 3; t++) {
#pragma unroll
            for (int dt = 0; dt < 4; dt++) {
                f32x4 o = Oa[dt][t];
                *(uint4*)&Vt[q16 * 68 + dt * 16 + g * 4] =
                    make_uint4(__float_as_uint(o[0]), __float_as_uint(o[1]),
                               __float_as_uint(o[2]), __float_as_uint(o[3]));
            }
#pragma unroll
            for (int j = 0; j < 4; j++) {
                uint4 u = *(uint4*)&Vt[q2 * 68 + j * 16 + c2 * 4];
                *(float4*)(ob + (size_t)(t * 16 + q2) * D_ + j * 16 + c2 * 4) =
                    make_float4(__uint_as_float(u.x), __uint_as_float(u.y),
                                __uint_as_float(u.z), __uint_as_float(u.w));
            }
        }
    }
}

// ---------------- Phase E: merge split partials, scatter into out ----------------
// Parallelism fix: 12 blocks per bh (4 q-rows x 64 d each); 64 lanes of a wave share one q
// -> the dead-split skip branch is wave-uniform; dead splits' Opart never touched.
__global__ __launch_bounds__(256) void kMerge(const float* __restrict__ Opart, const float* __restrict__ mpart,
                                              const float* __restrict__ lpart, const int* __restrict__ mtop,
                                              float* __restrict__ out, int nse) {
    int blk = blockIdx.x;
    int qg = blk % 12, bh = blk / 12;
    int b = bh >> 3, h = bh & 7;
    int q = qg * 4 + (threadIdx.x >> 6);
    int d = threadIdx.x & 63;
    if (q >= U_) return;
    const float* mp = mpart + (size_t)bh * nse * UP_ + q;
    const float* lp = lpart + (size_t)bh * nse * UP_ + q;
    float mmax = -INFINITY;
#pragma unroll 8
    for (int i = 0; i < nse; i++) mmax = fmaxf(mmax, mp[(size_t)i * UP_]);
    const float* op = Opart + ((size_t)bh * nse * UP_ + q) * D_ + d;
    float Ls = 0.f, val = 0.f;
    for (int i = 0; i < nse; i++) {
        float m = mp[(size_t)i * UP_];
        if (m == -INFINITY) continue;               // wave-uniform skip
        float w = __expf(m - mmax);
        Ls += lp[(size_t)i * UP_] * w;
        val += op[(size_t)i * UP_ * D_] * w;
    }
    int mrow = mtop[bh * U_ + q];
    out[(((size_t)b * L_ + mrow) * H_ + h) * D_ + d] = val / Ls;
}

extern "C" void kernel_launch(void* const* d_in, const int* in_sizes, int n_in,
                              void* d_out, int out_size, void* d_ws, size_t ws_size,
                              hipStream_t stream) {
    const float* Q = (const float*)d_in[0];
    const float* K = (const float*)d_in[1];
    const float* V = (const float*)d_in[2];
    const int* idx = (const int*)d_in[3];
    int S = in_sizes[3]; if (S > 45) S = 45;
    float* out = (float*)d_out;
    float* ws = (float*)d_ws;

    // Adaptive split count: 2*nsb effective splits; Opart = 128*2*nsb*48*64 floats.
    size_t wsf = ws_size / 4;
    int nsb = 16;
    while (nsb > 1) {
        size_t opart = (size_t)128 * (2 * nsb) * UP_ * D_;
        size_t need = 5760 + opart + 2 * (size_t)128 * (2 * nsb) * UP_;
        size_t needAB = 5760 + 524288 + 262144 + 368640;   // M + cs + k2 phase
        if (need <= wsf && needAB <= wsf) break;
        nsb >>= 1;
    }
    int nse = 2 * nsb;

    // layout: [mtop][ region shared by {M,cs,k2} (phases A-C) and {Opart,mpart,lpart} (phases D-E) ]
    int* mtop = (int*)ws;
    float* rest = ws + 5760;
    float* M = rest;
    float* cs = rest + 524288;
    float* k2 = rest + 524288 + 262144;
    float* Opart = rest;
    float* mpart = Opart + (size_t)128 * nse * UP_ * D_;
    float* lpart = mpart + (size_t)128 * nse * UP_;

    kK2  <<<B_ * H_,              256, 0, stream>>>(K, idx, S, k2);
    kM   <<<B_ * H_ * (L_ / 256), 256, 0, stream>>>(Q, k2, S, M);
    kTop <<<B_ * H_,              256, 0, stream>>>(M, mtop);
    kSum <<<B_ * H_ * NCHUNK,      64, 0, stream>>>(V, cs);
    kScan<<<B_ * H_,               64, 0, stream>>>(cs);
    kCum <<<B_ * H_ * NCHUNK,      64, 0, stream>>>(V, cs, out);
    kFlash<<<B_ * H_ * nsb,       128, 0, stream>>>(Q, K, V, mtop, Opart, mpart, lpart, nsb, L_ / nse);
    kMerge<<<B_ * H_ * 12,        256, 0, stream>>>(Opart, mpart, lpart, mtop, out, nse);
}

// Round 4
// 602.395 us; speedup vs baseline: 1.2192x; 1.0144x over previous
//
#include <hip/hip_runtime.h>
#include <math.h>

#define B_ 16
#define L_ 4096
#define H_ 8
#define D_ 64
#define HD_ (H_*D_)     // 512
#define U_ 45
#define UP_ 48
#define NCHUNK 32
#define CHLEN 128       // L_/NCHUNK
#define VTP 20          // Vt pitch in dwords (16B-aligned rows, conflict-light)
#define PP  20          // P  pitch in dwords

typedef __attribute__((ext_vector_type(8))) short short8v;  // 8 bf16 (4 VGPRs)
typedef __attribute__((ext_vector_type(4))) float f32x4;

__device__ inline unsigned int pk2(float a, float b) {
    return (__float_as_uint(b) & 0xFFFF0000u) | (__float_as_uint(a) >> 16);
}
__device__ inline short8v u4cast(uint4 u) {
    union { uint4 u4; short8v s8; } c; c.u4 = u; return c.s8;
}

// ---------------- Phase A0: K_sample^2 precompute (enables scalar loads in kM) ----------------
__global__ __launch_bounds__(256) void kK2(const float* __restrict__ K, const int* __restrict__ idx,
                                           int S, float* __restrict__ k2) {
    int bh = blockIdx.x;
    int b = bh >> 3, h = bh & 7;
    for (int i = threadIdx.x; i < S * D_; i += 256) {
        int s = i >> 6, d = i & 63;
        float kv = K[(((size_t)b * L_ + idx[s]) * H_ + h) * D_ + d];
        k2[(size_t)bh * (45 * 64) + i] = kv * kv;
    }
}

// ---------------- Phase A: sparsity measure M (fp32; 2 q-rows/thread, register-resident) ---------
// __launch_bounds__(256,2) gives the register allocator room to keep both Q rows in VGPRs
// (round-3 counter evidence: VGPR=56 forced Q re-loads every s-iter -> 2.7x VALU inflation).
// Per-row accumulation order is bitwise-identical to the previously passing kernel.
__global__ __launch_bounds__(256, 2) void kM(const float* __restrict__ Q, const float* __restrict__ k2g,
                                             int S, float* __restrict__ M) {
    int blk = blockIdx.x;
    int chunk = blk & 7;            // 8 chunks of 512 rows
    int bh = blk >> 3;
    int b = bh >> 3, h = bh & 7;
    int q0 = chunk * 512 + threadIdx.x;      // this thread: rows q0 and q0+256
    const float4* qpA = (const float4*)(Q + (((size_t)b * L_ + q0) * H_ + h) * D_);
    const float4* qpB = (const float4*)(Q + (((size_t)b * L_ + q0 + 256) * H_ + h) * D_);
    float4 qa[16], qb[16];
#pragma unroll
    for (int c = 0; c < 16; c++) { qa[c] = qpA[c]; qb[c] = qpB[c]; }
    const float4* kp0 = (const float4*)(k2g + (size_t)bh * (45 * 64));
    float mxa = -INFINITY, sma = 0.f;
    float mxb = -INFINITY, smb = 0.f;
    for (int s = 0; s < S; s++) {
        const float4* kp = kp0 + s * 16;   // uniform across wave -> scalar loads
        float a0 = 0, a1 = 0, a2 = 0, a3 = 0;
        float b0 = 0, b1 = 0, b2 = 0, b3 = 0;
#pragma unroll
        for (int c = 0; c < 16; c++) {
            float4 kv = kp[c];
            a0 += qa[c].x * kv.x; a1 += qa[c].y * kv.y;
            a2 += qa[c].z * kv.z; a3 += qa[c].w * kv.w;
            b0 += qb[c].x * kv.x; b1 += qb[c].y * kv.y;
            b2 += qb[c].z * kv.z; b3 += qb[c].w * kv.w;
        }
        float da = (a0 + a1) + (a2 + a3);
        float db = (b0 + b1) + (b2 + b3);
        mxa = fmaxf(mxa, da); sma += da;
        mxb = fmaxf(mxb, db); smb += db;
    }
    M[(size_t)bh * L_ + q0]       = mxa - sma * (1.0f / (float)L_);
    M[(size_t)bh * L_ + q0 + 256] = mxb - smb * (1.0f / (float)L_);
}

// ---------------- Phase B: top-45 per (b,h), register-resident iterative argmax ----------------
__global__ __launch_bounds__(256) void kTop(const float* __restrict__ M, int* __restrict__ mtop) {
    int bh = blockIdx.x, t = threadIdx.x;
    int lane = t & 63, wid = t >> 6;
    float mv[16];
#pragma unroll
    for (int w = 0; w < 16; w++) mv[w] = M[(size_t)bh * L_ + w * 256 + t];
    __shared__ float swv[4];
    __shared__ int swi[4];
    for (int it = 0; it < U_; it++) {
        float bv = -INFINITY; int bi = 1 << 30;
#pragma unroll
        for (int w = 0; w < 16; w++) {
            if (mv[w] > bv) { bv = mv[w]; bi = w * 256 + t; }
        }
#pragma unroll
        for (int off = 1; off < 64; off <<= 1) {
            float ov = __shfl_xor(bv, off); int oi = __shfl_xor(bi, off);
            if (ov > bv || (ov == bv && oi < bi)) { bv = ov; bi = oi; }
        }
        if (lane == 0) { swv[wid] = bv; swi[wid] = bi; }
        __syncthreads();
        float fv = swv[0]; int fi = swi[0];
        for (int w2 = 1; w2 < 4; w2++) {
            if (swv[w2] > fv || (swv[w2] == fv && swi[w2] < fi)) { fv = swv[w2]; fi = swi[w2]; }
        }
        if (t == 0) mtop[bh * U_ + it] = fi;
        int wr = fi >> 8;
        bool own = ((fi & 255) == t);
#pragma unroll
        for (int w = 0; w < 16; w++) mv[w] = (own && w == wr) ? -INFINITY : mv[w];
        __syncthreads();
    }
}

// ---------------- Phase C: chunked cumsum of V -> out ----------------
__global__ __launch_bounds__(64) void kSum(const float* __restrict__ V, float* __restrict__ cs) {
    int blk = blockIdx.x;
    int c = blk & 31, bh = blk >> 5;
    int b = bh >> 3, h = bh & 7;
    size_t base = (((size_t)b * L_ + c * CHLEN) * H_ + h) * D_ + threadIdx.x;
    float acc = 0.f;
#pragma unroll 8
    for (int i = 0; i < CHLEN; i++) acc += V[base + (size_t)i * HD_];
    cs[((size_t)bh * NCHUNK + c) * D_ + threadIdx.x] = acc;
}

__global__ __launch_bounds__(64) void kScan(float* __restrict__ cs) {
    int bh = blockIdx.x;
    int d = threadIdx.x;
    float run = 0.f;
    for (int c = 0; c < NCHUNK; c++) {
        size_t i = ((size_t)bh * NCHUNK + c) * D_ + d;
        float t = cs[i]; cs[i] = run; run += t;
    }
}

__global__ __launch_bounds__(64) void kCum(const float* __restrict__ V, const float* __restrict__ cs,
                                           float* __restrict__ out) {
    int blk = blockIdx.x;
    int c = blk & 31, bh = blk >> 5;
    int b = bh >> 3, h = bh & 7;
    size_t base = (((size_t)b * L_ + c * CHLEN) * H_ + h) * D_ + threadIdx.x;
    float acc = cs[((size_t)bh * NCHUNK + c) * D_ + threadIdx.x];
#pragma unroll 4
    for (int i = 0; i < CHLEN; i++) {
        acc += V[base + (size_t)i * HD_];
        out[base + (size_t)i * HD_] = acc;
    }
}

// ---------------- Phase D: per-wave-independent split-K flash attention (MFMA bf16) ----------------
__global__ __launch_bounds__(128) void kFlash(const float* __restrict__ Q, const float* __restrict__ K,
                                              const float* __restrict__ V, const int* __restrict__ mtop,
                                              float* __restrict__ Opart, float* __restrict__ mpart,
                                              float* __restrict__ lpart, int nsb, int wkspan) {
    int blk = blockIdx.x;
    int ks = blk % nsb;
    int bh = blk / nsb;
    int b = bh >> 3, h = bh & 7;
    int tid = threadIdx.x, wave = tid >> 6, lane = tid & 63;
    int q16 = lane & 15, g = lane >> 4;

    __shared__ __align__(16) unsigned int VtS[2][64 * VTP];   // per-wave V^T tile (also O bounce)
    __shared__ __align__(16) unsigned int PS[2][UP_ * PP];    // per-wave P tile [q][k] bf16
    __shared__ int mt[UP_];
    __shared__ int kmaxs;

    unsigned int* Vt = VtS[wave];
    unsigned int* P = PS[wave];

    if (tid < UP_) mt[tid] = (tid < U_) ? mtop[bh * U_ + tid] : -1;
    __syncthreads();
    if (tid == 0) {
        int km = 0;
        for (int u = 0; u < U_; u++) km = max(km, mt[u] + 1);
        kmaxs = km;
    }

    // Q fragments in registers (B-frag: q = lane&15 per tile, d = (lane>>4)*8 + s*32 + j), pre-scaled.
    int mtr[3];
    short8v qf[3][2];
#pragma unroll
    for (int t = 0; t < 3; t++) {
        int qi = t * 16 + q16;
        mtr[t] = mt[qi];
        int r = mtr[t] < 0 ? 0 : mtr[t];
        const float* qrow = Q + (((size_t)b * L_ + r) * H_ + h) * D_;
#pragma unroll
        for (int s = 0; s < 2; s++) {
            int d0 = s * 32 + g * 8;
            float4 f0 = *(const float4*)(qrow + d0);
            float4 f1 = *(const float4*)(qrow + d0 + 4);
            uint4 u;
            u.x = pk2(f0.x * 0.125f, f0.y * 0.125f);
            u.y = pk2(f0.z * 0.125f, f0.w * 0.125f);
            u.z = pk2(f1.x * 0.125f, f1.y * 0.125f);
            u.w = pk2(f1.z * 0.125f, f1.w * 0.125f);
            qf[t][s] = u4cast(u);
        }
    }
    __syncthreads();

    f32x4 Oa[4][3];   // [dtile][qtile]; C: q = lane&15, d = dt*16 + (lane>>4)*4 + reg
#pragma unroll
    for (int dt = 0; dt < 4; dt++)
#pragma unroll
        for (int t = 0; t < 3; t++) Oa[dt][t] = (f32x4){0.f, 0.f, 0.f, 0.f};
    float mrow[3] = {-INFINITY, -INFINITY, -INFINITY};
    float lrow[3] = {0.f, 0.f, 0.f};

    int ko = (ks * 2 + wave) * wkspan;
    int kend = min(kmaxs, ko + wkspan);

    for (int jt = ko; jt < kend; jt += 32) {
        // ---- issue V loads early (consumed after GEMM1/softmax) ----
        const float* vrow0 = V + (((size_t)b * L_ + jt + 2 * q16) * H_ + h) * D_;
        const float* vrow1 = vrow0 + HD_;
        float4 va[4], vb[4];
#pragma unroll
        for (int i = 0; i < 4; i++) {
            int d0 = i * 16 + g * 4;
            va[i] = *(const float4*)(vrow0 + d0);
            vb[i] = *(const float4*)(vrow1 + d0);
        }
        // ---- K fragments from global + GEMM1 ----
        f32x4 Sa[3][2];
#pragma unroll
        for (int t = 0; t < 3; t++)
#pragma unroll
            for (int n = 0; n < 2; n++) Sa[t][n] = (f32x4){0.f, 0.f, 0.f, 0.f};
#pragma unroll
        for (int s = 0; s < 2; s++) {
            short8v kf[2];
#pragma unroll
            for (int n = 0; n < 2; n++) {
                const float* krow = K + (((size_t)b * L_ + jt + n * 16 + q16) * H_ + h) * D_ + s * 32 + g * 8;
                float4 f0 = *(const float4*)krow;
                float4 f1 = *(const float4*)(krow + 4);
                uint4 u;
                u.x = pk2(f0.x, f0.y); u.y = pk2(f0.z, f0.w);
                u.z = pk2(f1.x, f1.y); u.w = pk2(f1.z, f1.w);
                kf[n] = u4cast(u);
            }
#pragma unroll
            for (int t = 0; t < 3; t++)
#pragma unroll
                for (int n = 0; n < 2; n++)
                    Sa[t][n] = __builtin_amdgcn_mfma_f32_16x16x32_bf16(kf[n], qf[t][s], Sa[t][n], 0, 0, 0);
        }
        // ---- online softmax per q-tile (keys in-lane + shfl_xor over groups) ----
#pragma unroll
        for (int t = 0; t < 3; t++) {
            int limit = mtr[t];
            int kb = jt + g * 4;
            float p[2][4];
            float pmax = -INFINITY;
#pragma unroll
            for (int n = 0; n < 2; n++)
#pragma unroll
                for (int r = 0; r < 4; r++) {
                    float sv = (kb + n * 16 + r <= limit) ? Sa[t][n][r] : -INFINITY;
                    p[n][r] = sv;
                    pmax = fmaxf(pmax, sv);
                }
            pmax = fmaxf(pmax, __shfl_xor(pmax, 16));
            pmax = fmaxf(pmax, __shfl_xor(pmax, 32));
            float nm = fmaxf(mrow[t], pmax);
            float alpha = (nm == -INFINITY) ? 1.f : __expf(mrow[t] - nm);
            mrow[t] = nm;
            float rs = 0.f;
#pragma unroll
            for (int n = 0; n < 2; n++)
#pragma unroll
                for (int r = 0; r < 4; r++) {
                    float pv = (p[n][r] == -INFINITY) ? 0.f : __expf(p[n][r] - nm);
                    p[n][r] = pv; rs += pv;
                }
            rs += __shfl_xor(rs, 16);
            rs += __shfl_xor(rs, 32);
            lrow[t] = lrow[t] * alpha + rs;
            int qi = t * 16 + q16;
#pragma unroll
            for (int n = 0; n < 2; n++) {
                *(uint2*)&P[qi * PP + n * 8 + 2 * g] =
                    make_uint2(pk2(p[n][0], p[n][1]), pk2(p[n][2], p[n][3]));
            }
#pragma unroll
            for (int dt = 0; dt < 4; dt++)
#pragma unroll
                for (int r = 0; r < 4; r++) Oa[dt][t][r] *= alpha;
        }
        // ---- stage V^T (keys packed in pairs along rows of d) ----
#pragma unroll
        for (int i = 0; i < 4; i++) {
            int d0 = i * 16 + g * 4;
#pragma unroll
            for (int c = 0; c < 4; c++) {
                float fa = (&va[i].x)[c], fb = (&vb[i].x)[c];
                Vt[(d0 + c) * VTP + q16] = pk2(fa, fb);
            }
        }
        // ---- GEMM2: O^T += Vt . P ----
        short8v pb[3];
#pragma unroll
        for (int t = 0; t < 3; t++)
            pb[t] = u4cast(*(uint4*)&P[(t * 16 + q16) * PP + g * 4]);
#pragma unroll
        for (int dt = 0; dt < 4; dt++) {
            short8v vf = u4cast(*(uint4*)&Vt[(dt * 16 + q16) * VTP + g * 4]);
#pragma unroll
            for (int t = 0; t < 3; t++)
                Oa[dt][t] = __builtin_amdgcn_mfma_f32_16x16x32_bf16(vf, pb[t], Oa[dt][t], 0, 0, 0);
        }
    }

    // ---- epilogue: write m/l always; O only if this wave covered any keys ----
    int nse = nsb * 2;
    int e = ks * 2 + wave;
    if (g == 0) {
#pragma unroll
        for (int t = 0; t < 3; t++) {
            int qi = t * 16 + q16;
            mpart[(size_t)(bh * nse + e) * UP_ + qi] = mrow[t];
            lpart[(size_t)(bh * nse + e) * UP_ + qi] = lrow[t];
        }
    }
    if (kend > ko) {
        float* ob = Opart + ((size_t)(bh * nse + e)) * UP_ * D_;
        int q2 = lane >> 2, c2 = lane & 3;
#pragma unroll
        for (int t = 0; t < 3; t++) {
#pragma unroll
            for (int dt = 0; dt < 4; dt++) {
                f32x4 o = Oa[dt][t];
                *(uint4*)&Vt[q16 * 68 + dt * 16 + g * 4] =
                    make_uint4(__float_as_uint(o[0]), __float_as_uint(o[1]),
                               __float_as_uint(o[2]), __float_as_uint(o[3]));
            }
#pragma unroll
            for (int j = 0; j < 4; j++) {
                uint4 u = *(uint4*)&Vt[q2 * 68 + j * 16 + c2 * 4];
                *(float4*)(ob + (size_t)(t * 16 + q2) * D_ + j * 16 + c2 * 4) =
                    make_float4(__uint_as_float(u.x), __uint_as_float(u.y),
                                __uint_as_float(u.z), __uint_as_float(u.w));
            }
        }
    }
}

// ---------------- Phase E: merge split partials, scatter into out ----------------
__global__ __launch_bounds__(256) void kMerge(const float* __restrict__ Opart, const float* __restrict__ mpart,
                                              const float* __restrict__ lpart, const int* __restrict__ mtop,
                                              float* __restrict__ out, int nse) {
    int blk = blockIdx.x;
    int qg = blk % 12, bh = blk / 12;
    int b = bh >> 3, h = bh & 7;
    int q = qg * 4 + (threadIdx.x >> 6);
    int d = threadIdx.x & 63;
    if (q >= U_) return;
    const float* mp = mpart + (size_t)bh * nse * UP_ + q;
    const float* lp = lpart + (size_t)bh * nse * UP_ + q;
    float mmax = -INFINITY;
#pragma unroll 8
    for (int i = 0; i < nse; i++) mmax = fmaxf(mmax, mp[(size_t)i * UP_]);
    const float* op = Opart + ((size_t)bh * nse * UP_ + q) * D_ + d;
    float Ls = 0.f, val = 0.f;
    for (int i = 0; i < nse; i++) {
        float m = mp[(size_t)i * UP_];
        if (m == -INFINITY) continue;               // wave-uniform skip
        float w = __expf(m - mmax);
        Ls += lp[(size_t)i * UP_] * w;
        val += op[(size_t)i * UP_ * D_] * w;
    }
    int mrow = mtop[bh * U_ + q];
    out[(((size_t)b * L_ + mrow) * H_ + h) * D_ + d] = val / Ls;
}

extern "C" void kernel_launch(void* const* d_in, const int* in_sizes, int n_in,
                              void* d_out, int out_size, void* d_ws, size_t ws_size,
                              hipStream_t stream) {
    const float* Q = (const float*)d_in[0];
    const float* K = (const float*)d_in[1];
    const float* V = (const float*)d_in[2];
    const int* idx = (const int*)d_in[3];
    int S = in_sizes[3]; if (S > 45) S = 45;
    float* out = (float*)d_out;
    float* ws = (float*)d_ws;

    // Adaptive split count: 2*nsb effective splits; Opart = 128*2*nsb*48*64 floats.
    size_t wsf = ws_size / 4;
    int nsb = 16;
    while (nsb > 1) {
        size_t opart = (size_t)128 * (2 * nsb) * UP_ * D_;
        size_t need = 5760 + opart + 2 * (size_t)128 * (2 * nsb) * UP_;
        size_t needAB = 5760 + 524288 + 262144 + 368640;   // M + cs + k2 phase
        if (need <= wsf && needAB <= wsf) break;
        nsb >>= 1;
    }
    int nse = 2 * nsb;

    // layout: [mtop][ region shared by {M,cs,k2} (phases A-C) and {Opart,mpart,lpart} (phases D-E) ]
    int* mtop = (int*)ws;
    float* rest = ws + 5760;
    float* M = rest;
    float* cs = rest + 524288;
    float* k2 = rest + 524288 + 262144;
    float* Opart = rest;
    float* mpart = Opart + (size_t)128 * nse * UP_ * D_;
    float* lpart = mpart + (size_t)128 * nse * UP_;

    kK2  <<<B_ * H_,              256, 0, stream>>>(K, idx, S, k2);
    kM   <<<B_ * H_ * (L_ / 512), 256, 0, stream>>>(Q, k2, S, M);
    kTop <<<B_ * H_,              256, 0, stream>>>(M, mtop);
    kSum <<<B_ * H_ * NCHUNK,      64, 0, stream>>>(V, cs);
    kScan<<<B_ * H_,               64, 0, stream>>>(cs);
    kCum <<<B_ * H_ * NCHUNK,      64, 0, stream>>>(V, cs, out);
    kFlash<<<B_ * H_ * nsb,       128, 0, stream>>>(Q, K, V, mtop, Opart, mpart, lpart, nsb, L_ / nse);
    kMerge<<<B_ * H_ * 12,        256, 0, stream>>>(Opart, mpart, lpart, mtop, out, nse);
}